// Round 1
// baseline (175.105 us; speedup 1.0000x reference)
//
#include <hip/hip_runtime.h>
#include <cstdint>

#define BATCH 4
#define TQ 256
#define TK 256
#define DIM 256
#define HD 256

typedef _Float16 f16x8 __attribute__((ext_vector_type(8)));
typedef float f32x4 __attribute__((ext_vector_type(4)));

union U4H8 { uint4 u; f16x8 v; };

__device__ __forceinline__ unsigned short f2h(float f) {
    _Float16 h = (_Float16)f;
    unsigned short u;
    __builtin_memcpy(&u, &h, 2);
    return u;
}

__device__ __forceinline__ uint32_t pk2h(float a, float b) {
#if __has_builtin(__builtin_amdgcn_cvt_pkrtz)
    auto r = __builtin_amdgcn_cvt_pkrtz(a, b);
    uint32_t w;
    __builtin_memcpy(&w, &r, 4);
    return w;
#else
    return (uint32_t)f2h(a) | ((uint32_t)f2h(b) << 16);
#endif
}

// qh = queries @ W1[256:512], kh = keys @ W1[0:256]  (fp32, exact)
// grid 256 blocks x 256 threads; 8 output rows per block.
__global__ __launch_bounds__(256) void prep_qk(
    const float* __restrict__ queries, const float* __restrict__ keys,
    const float* __restrict__ W1, float* __restrict__ qh, float* __restrict__ kh) {
    int i = blockIdx.x;
    int t = threadIdx.x;
    bool isQ = i < 128;
    int r0 = (isQ ? i : i - 128) * 8;
    const float* X = isQ ? queries : keys;
    const float* W = W1 + (isQ ? DIM * HD : 0);
    float* O = isQ ? qh : kh;
    __shared__ float xs[8][DIM];
#pragma unroll
    for (int r = 0; r < 8; ++r) xs[r][t] = X[(r0 + r) * DIM + t];
    __syncthreads();
    float acc[8] = {0.f, 0.f, 0.f, 0.f, 0.f, 0.f, 0.f, 0.f};
    for (int d = 0; d < DIM; ++d) {
        float w = W[d * HD + t];  // coalesced across t
#pragma unroll
        for (int r = 0; r < 8; ++r) acc[r] = fmaf(xs[r][d], w, acc[r]);
    }
#pragma unroll
    for (int r = 0; r < 8; ++r) O[(r0 + r) * HD + t] = acc[r];
}

// W2T[n][c] = (f16)W2[c][n]; 32x32 LDS tiles, grid 64 x 256.
__global__ __launch_bounds__(256) void w2_transpose(
    const float* __restrict__ W2, unsigned short* __restrict__ W2T) {
    __shared__ float tile[32][33];
    int tx = threadIdx.x & 31, ty = threadIdx.x >> 5;
    int tc = (blockIdx.x & 7) * 32, tn = (blockIdx.x >> 3) * 32;
#pragma unroll
    for (int i = 0; i < 4; ++i)
        tile[ty + i * 8][tx] = W2[(tc + ty + i * 8) * HD + tn + tx];
    __syncthreads();
#pragma unroll
    for (int i = 0; i < 4; ++i)
        W2T[(tn + ty + i * 8) * HD + tc + tx] = f2h(tile[tx][ty + i * 8]);
}

// scores[b][q][k] = W3 . relu(W2 . relu(qh[q]+kh[k]+b1) + b2) + b3
// block = (b, q, 64-wide k chunk); 4 waves, wave w owns n-slice [w*64, w*64+64).
// A (h1, 64x256) generated on-the-fly into fragment-ordered LDS, double-buffered.
// B (W2T) fragments loaded straight from global (L2-resident 128 KB).
__global__ __launch_bounds__(256) void mlp_scores(
    const float* __restrict__ qh, const float* __restrict__ kh,
    const unsigned short* __restrict__ W2T,
    const float* __restrict__ b1, const float* __restrict__ b2,
    const float* __restrict__ W3, const float* __restrict__ b3,
    const int* __restrict__ qlens, const int* __restrict__ klens,
    float* __restrict__ scores) {
    int bid = blockIdx.x;
    int b = bid >> 10;
    int rem = bid & 1023;
    int q = rem >> 2;
    int kc = (rem & 3) << 6;
    if (q >= qlens[b]) return;     // masked q row: softmax_pv writes zeros
    if (kc >= klens[b]) return;    // fully masked k chunk: never read

    __shared__ float qhb[HD];             // qh row + b1
    __shared__ uint4 Afrag[2][4][64];     // [buf][m-tile][lane] fragment-ordered f16x8
    __shared__ float sc[4][64];           // per-wave score partials

    int t = threadIdx.x;
    int wid = t >> 6, lane = t & 63;
    int col = lane & 15, quad = lane >> 4;

    qhb[t] = qh[((b * TQ + q) * HD) + t] + b1[t];

    // staging role: thread t -> pair p = t>>2, c-octet j8 = t&3
    int p = t >> 2, j8 = t & 3;
    const float* krow = kh + ((b * TK + kc + p) * HD) + j8 * 8;
    uint4* aslot0 = &Afrag[0][p >> 4][(p & 15) | (j8 << 4)];
    uint4* aslot1 = &Afrag[1][p >> 4][(p & 15) | (j8 << 4)];

    int nb = wid * 64;
    const uint4* w2rows[4];
    float b2v[4], w3v[4];
#pragma unroll
    for (int nt = 0; nt < 4; ++nt) {
        int n = nb + nt * 16 + col;
        w2rows[nt] = (const uint4*)(W2T + n * HD) + quad;  // +quad: k-offset quad*8
        b2v[nt] = b2[n];
        w3v[nt] = W3[n];
    }

    f32x4 acc[4][4] = {};

    auto stage = [&](int buf, int c0) {
        const float4 k0 = *(const float4*)(krow + c0);
        const float4 k1 = *(const float4*)(krow + c0 + 4);
        const float4 q0 = *(const float4*)(qhb + c0 + j8 * 8);
        const float4 q1 = *(const float4*)(qhb + c0 + j8 * 8 + 4);
        float h0 = fmaxf(k0.x + q0.x, 0.f), h1v = fmaxf(k0.y + q0.y, 0.f);
        float h2 = fmaxf(k0.z + q0.z, 0.f), h3 = fmaxf(k0.w + q0.w, 0.f);
        float h4 = fmaxf(k1.x + q1.x, 0.f), h5 = fmaxf(k1.y + q1.y, 0.f);
        float h6 = fmaxf(k1.z + q1.z, 0.f), h7 = fmaxf(k1.w + q1.w, 0.f);
        uint4 w;
        w.x = pk2h(h0, h1v); w.y = pk2h(h2, h3);
        w.z = pk2h(h4, h5);  w.w = pk2h(h6, h7);
        *(buf ? aslot1 : aslot0) = w;
    };

    __syncthreads();   // qhb visible
    stage(0, 0);
    __syncthreads();   // buffer 0 staged

    for (int s = 0; s < 8; ++s) {
        int cur = s & 1;
        if (s < 7) stage(cur ^ 1, (s + 1) * 32);
        f16x8 bfr[4];
#pragma unroll
        for (int nt = 0; nt < 4; ++nt) {
            U4H8 bu;
            bu.u = w2rows[nt][s * 4];  // 4 uint4 = 32 f16 per k-step
            bfr[nt] = bu.v;
        }
#pragma unroll
        for (int mt = 0; mt < 4; ++mt) {
            U4H8 au;
            au.u = Afrag[cur][mt][lane];
#pragma unroll
            for (int nt = 0; nt < 4; ++nt)
                acc[mt][nt] = __builtin_amdgcn_mfma_f32_16x16x32_f16(
                    au.v, bfr[nt], acc[mt][nt], 0, 0, 0);
        }
        __syncthreads();  // next buffer staged; current buffer free to overwrite
    }

    // epilogue: relu(+b2) * W3, reduce over n
    float part[4][4];  // [m-tile][reg-row]
#pragma unroll
    for (int mt = 0; mt < 4; ++mt)
#pragma unroll
        for (int r = 0; r < 4; ++r) {
            float pa = 0.f;
#pragma unroll
            for (int nt = 0; nt < 4; ++nt) {
                float v = acc[mt][nt][r] + b2v[nt];
                v = fmaxf(v, 0.f);
                pa = fmaf(v, w3v[nt], pa);
            }
            part[mt][r] = pa;
        }
#pragma unroll
    for (int off = 1; off < 16; off <<= 1)
#pragma unroll
        for (int mt = 0; mt < 4; ++mt)
#pragma unroll
            for (int r = 0; r < 4; ++r)
                part[mt][r] += __shfl_xor(part[mt][r], off, 64);
    if (col == 0) {
#pragma unroll
        for (int mt = 0; mt < 4; ++mt)
#pragma unroll
            for (int r = 0; r < 4; ++r)
                sc[wid][mt * 16 + quad * 4 + r] = part[mt][r];
    }
    __syncthreads();
    if (t < 64) {
        float s = sc[0][t] + sc[1][t] + sc[2][t] + sc[3][t] + b3[0];
        scores[((b * TQ + q) * TK) + kc + t] = s;
    }
}

// masked softmax over k, then out[b,q,:] = probs @ keys[b]
__global__ __launch_bounds__(256) void softmax_pv(
    const float* __restrict__ scores, const float* __restrict__ keys,
    const int* __restrict__ qlens, const int* __restrict__ klens,
    float* __restrict__ out) {
    int bid = blockIdx.x;
    int b = bid >> 8, q = bid & 255;
    int t = threadIdx.x;
    float* orow = out + ((b * TQ + q) * DIM);
    if (q >= qlens[b]) { orow[t] = 0.f; return; }
    int klen = klens[b];
    const float* srow = scores + ((b * TQ + q) * TK);
    __shared__ float red[4];
    __shared__ float pl[TK];
    int wid = t >> 6, lane = t & 63;

    float s = (t < klen) ? srow[t] : -3.4e38f;
    float m = s;
#pragma unroll
    for (int off = 1; off < 64; off <<= 1) m = fmaxf(m, __shfl_xor(m, off, 64));
    if (lane == 0) red[wid] = m;
    __syncthreads();
    m = fmaxf(fmaxf(red[0], red[1]), fmaxf(red[2], red[3]));
    float pv = (t < klen) ? __expf(s - m) : 0.f;
    float sum = pv;
#pragma unroll
    for (int off = 1; off < 64; off <<= 1) sum += __shfl_xor(sum, off, 64);
    __syncthreads();
    if (lane == 0) red[wid] = sum;
    __syncthreads();
    float denom = red[0] + red[1] + red[2] + red[3];
    pl[t] = pv / denom;
    __syncthreads();

    float acc = 0.f;
    const float* kp = keys + b * TK * DIM + t;  // coalesced: t = channel
#pragma unroll 4
    for (int k = 0; k < klen; ++k) acc = fmaf(pl[k], kp[k * DIM], acc);
    orow[t] = acc;
}

extern "C" void kernel_launch(void* const* d_in, const int* in_sizes, int n_in,
                              void* d_out, int out_size, void* d_ws, size_t ws_size,
                              hipStream_t stream) {
    (void)in_sizes; (void)n_in; (void)out_size; (void)ws_size;
    const float* queries = (const float*)d_in[0];
    const float* keys    = (const float*)d_in[1];
    const int*   qlens   = (const int*)d_in[2];
    const int*   klens   = (const int*)d_in[3];
    const float* W1      = (const float*)d_in[4];
    const float* b1      = (const float*)d_in[5];
    const float* W2      = (const float*)d_in[6];
    const float* b2      = (const float*)d_in[7];
    const float* W3      = (const float*)d_in[8];
    const float* b3      = (const float*)d_in[9];
    float* out = (float*)d_out;

    float* qh     = (float*)d_ws;                 // 4*256*256 f32 = 1 MB
    float* kh     = qh + BATCH * TQ * HD;         // 1 MB
    float* scores = kh + BATCH * TK * HD;         // 1 MB
    unsigned short* W2T = (unsigned short*)(scores + BATCH * TQ * TK);  // 128 KB, 16B-aligned

    prep_qk<<<256, 256, 0, stream>>>(queries, keys, W1, qh, kh);
    w2_transpose<<<64, 256, 0, stream>>>(W2, W2T);
    mlp_scores<<<BATCH * TQ * (TK / 64), 256, 0, stream>>>(
        qh, kh, W2T, b1, b2, W3, b3, qlens, klens, scores);
    softmax_pv<<<BATCH * TQ, 256, 0, stream>>>(scores, keys, qlens, klens, out);
}

// Round 2
// 167.548 us; speedup vs baseline: 1.0451x; 1.0451x over previous
//
#include <hip/hip_runtime.h>
#include <cstdint>

#define BATCH 4
#define TQ 256
#define TK 256
#define DIM 256
#define HD 256

typedef _Float16 f16x8 __attribute__((ext_vector_type(8)));
typedef float f32x4 __attribute__((ext_vector_type(4)));

union U4H8 { uint4 u; f16x8 v; };

__device__ __forceinline__ unsigned short f2h(float f) {
    _Float16 h = (_Float16)f;
    unsigned short u;
    __builtin_memcpy(&u, &h, 2);
    return u;
}

__device__ __forceinline__ uint32_t pk2h(float a, float b) {
    auto r = __builtin_amdgcn_cvt_pkrtz(a, b);
    uint32_t w;
    __builtin_memcpy(&w, &r, 4);
    return w;
}

// qh = queries @ W1[256:512] + b1 (bias folded), kh = keys @ W1[0:256]  (fp32)
// grid 256 blocks x 256 threads; 8 output rows per block.
__global__ __launch_bounds__(256) void prep_qk(
    const float* __restrict__ queries, const float* __restrict__ keys,
    const float* __restrict__ W1, const float* __restrict__ b1,
    float* __restrict__ qh, float* __restrict__ kh) {
    int i = blockIdx.x;
    int t = threadIdx.x;
    bool isQ = i < 128;
    int r0 = (i & 127) * 8;
    const float* X = isQ ? queries : keys;
    const float* W = W1 + (isQ ? DIM * HD : 0);
    float* O = isQ ? qh : kh;
    __shared__ float xs[8][DIM];
#pragma unroll
    for (int r = 0; r < 8; ++r) xs[r][t] = X[(r0 + r) * DIM + t];
    __syncthreads();
    float acc[8] = {0.f, 0.f, 0.f, 0.f, 0.f, 0.f, 0.f, 0.f};
#pragma unroll 4
    for (int d = 0; d < DIM; ++d) {
        float w = W[d * HD + t];  // coalesced across t
#pragma unroll
        for (int r = 0; r < 8; ++r) acc[r] = fmaf(xs[r][d], w, acc[r]);
    }
    float bias = isQ ? b1[t] : 0.f;
#pragma unroll
    for (int r = 0; r < 8; ++r) O[(r0 + r) * HD + t] = acc[r] + bias;
}

// W2T[n][c] = (f16)W2[c][n]; 32x32 LDS tiles, grid 64 x 256.
__global__ __launch_bounds__(256) void w2_transpose(
    const float* __restrict__ W2, unsigned short* __restrict__ W2T) {
    __shared__ float tile[32][33];
    int tx = threadIdx.x & 31, ty = threadIdx.x >> 5;
    int tc = (blockIdx.x & 7) * 32, tn = (blockIdx.x >> 3) * 32;
#pragma unroll
    for (int i = 0; i < 4; ++i)
        tile[ty + i * 8][tx] = W2[(tc + ty + i * 8) * HD + tn + tx];
    __syncthreads();
#pragma unroll
    for (int i = 0; i < 4; ++i)
        W2T[(tn + ty + i * 8) * HD + tc + tx] = f2h(tile[tx][ty + i * 8]);
}

// scores[b][q][k] = W3 . relu(W2 . relu(qh'[q]+kh[k]) + b2) + b3   (b1 folded into qh')
// block = (b, q, 64-wide k chunk); 4 waves, wave w owns n-slice [w*64, w*64+64).
// Phase 1: stage the FULL 64x256 A tile (f16, fragment-ordered) — all loads
//          issued up-front, ONE barrier. Phase 2: barrier-free unrolled MFMA.
__global__ __launch_bounds__(256, 4) void mlp_scores(
    const float* __restrict__ qh, const float* __restrict__ kh,
    const unsigned short* __restrict__ W2T,
    const float* __restrict__ b2, const float* __restrict__ W3,
    const float* __restrict__ b3,
    const int* __restrict__ qlens, const int* __restrict__ klens,
    float* __restrict__ scores) {
    int bid = blockIdx.x;
    int b = bid >> 10;
    int rem = bid & 1023;
    int q = rem >> 2;
    int kc = (rem & 3) << 6;
    if (q >= qlens[b]) return;     // masked q row: softmax_pv writes zeros
    if (kc >= klens[b]) return;    // fully masked k chunk: never read

    __shared__ uint4 Afrag[8][4][64];     // [k-step][m-tile][lane] f16x8, 32 KB
    __shared__ float sc[4][64];           // per-wave score partials

    int t = threadIdx.x;
    int wid = t >> 6, lane = t & 63;
    int col = lane & 15, quad = lane >> 4;

    // ---- phase 1: stage A. thread t -> row p = t>>2, c-octet j8 = t&3 ----
    int p = t >> 2, j8 = t & 3;
    const float* krow = kh + (b * TK + kc + p) * HD + j8 * 8;
    const float* qrow = qh + (b * TQ + q) * HD + j8 * 8;   // b1 pre-folded
    uint4* aslot = &Afrag[0][p >> 4][(p & 15) | (j8 << 4)];
#pragma unroll
    for (int s = 0; s < 8; ++s) {
        const float4 k0 = *(const float4*)(krow + s * 32);
        const float4 k1 = *(const float4*)(krow + s * 32 + 4);
        const float4 q0 = *(const float4*)(qrow + s * 32);
        const float4 q1 = *(const float4*)(qrow + s * 32 + 4);
        uint4 w;
        w.x = pk2h(fmaxf(k0.x + q0.x, 0.f), fmaxf(k0.y + q0.y, 0.f));
        w.y = pk2h(fmaxf(k0.z + q0.z, 0.f), fmaxf(k0.w + q0.w, 0.f));
        w.z = pk2h(fmaxf(k1.x + q1.x, 0.f), fmaxf(k1.y + q1.y, 0.f));
        w.w = pk2h(fmaxf(k1.z + q1.z, 0.f), fmaxf(k1.w + q1.w, 0.f));
        aslot[s * 256] = w;   // stride between k-steps = 4*64 uint4
    }

    int nb = wid * 64;
    const uint4* w2r[4];
    float b2v[4], w3v[4];
#pragma unroll
    for (int nt = 0; nt < 4; ++nt) {
        int n = nb + nt * 16 + col;
        w2r[nt] = (const uint4*)(W2T + n * HD) + quad;  // +quad: k-offset quad*8
        b2v[nt] = b2[n];
        w3v[nt] = W3[n];
    }

    f32x4 acc[4][4] = {};
    __syncthreads();   // the ONLY staging barrier

    // ---- phase 2: barrier-free fully-unrolled MFMA ----
#pragma unroll
    for (int s = 0; s < 8; ++s) {
        f16x8 bfr[4];
#pragma unroll
        for (int nt = 0; nt < 4; ++nt) {
            U4H8 bu;
            bu.u = w2r[nt][s * 4];  // 4 uint4 = 32 f16 per k-step
            bfr[nt] = bu.v;
        }
#pragma unroll
        for (int mt = 0; mt < 4; ++mt) {
            U4H8 au;
            au.u = Afrag[s][mt][lane];
#pragma unroll
            for (int nt = 0; nt < 4; ++nt)
                acc[mt][nt] = __builtin_amdgcn_mfma_f32_16x16x32_f16(
                    au.v, bfr[nt], acc[mt][nt], 0, 0, 0);
        }
    }

    // epilogue: relu(+b2) * W3, reduce over n
    float part[4][4];  // [m-tile][reg-row]
#pragma unroll
    for (int mt = 0; mt < 4; ++mt)
#pragma unroll
        for (int r = 0; r < 4; ++r) {
            float pa = 0.f;
#pragma unroll
            for (int nt = 0; nt < 4; ++nt) {
                float v = acc[mt][nt][r] + b2v[nt];
                v = fmaxf(v, 0.f);
                pa = fmaf(v, w3v[nt], pa);
            }
            part[mt][r] = pa;
        }
#pragma unroll
    for (int off = 1; off < 16; off <<= 1)
#pragma unroll
        for (int mt = 0; mt < 4; ++mt)
#pragma unroll
            for (int r = 0; r < 4; ++r)
                part[mt][r] += __shfl_xor(part[mt][r], off, 64);
    if (col == 0) {
#pragma unroll
        for (int mt = 0; mt < 4; ++mt)
#pragma unroll
            for (int r = 0; r < 4; ++r)
                sc[wid][mt * 16 + quad * 4 + r] = part[mt][r];
    }
    __syncthreads();
    if (t < 64) {
        float s = sc[0][t] + sc[1][t] + sc[2][t] + sc[3][t] + b3[0];
        scores[((b * TQ + q) * TK) + kc + t] = s;
    }
}

// Fused masked softmax + PV, 4 q-rows per block (wave w owns row qg+w).
// keys streamed once per 4 rows -> 4x less L2 traffic than row-per-block.
#define QG 4
__global__ __launch_bounds__(256) void softmax_pv(
    const float* __restrict__ scores, const float* __restrict__ keys,
    const int* __restrict__ qlens, const int* __restrict__ klens,
    float* __restrict__ out) {
    int bid = blockIdx.x;
    int b = bid >> 6, qg = (bid & 63) * QG;
    int t = threadIdx.x, wid = t >> 6, lane = t & 63;
    int qlen = qlens[b], klen = klens[b];
    __shared__ float pl[QG][TK];

    int q = qg + wid;
    const float* srow = scores + (b * TQ + q) * TK;
    bool qmask = (q >= qlen);
    float sv[4];
#pragma unroll
    for (int i = 0; i < 4; ++i) {
        int k = lane + i * 64;
        sv[i] = (!qmask && k < klen) ? srow[k] : -3.4e38f;
    }
    float m = fmaxf(fmaxf(sv[0], sv[1]), fmaxf(sv[2], sv[3]));
#pragma unroll
    for (int off = 1; off < 64; off <<= 1) m = fmaxf(m, __shfl_xor(m, off, 64));
    float pvv[4], sum = 0.f;
#pragma unroll
    for (int i = 0; i < 4; ++i) {
        pvv[i] = (sv[i] > -1e37f) ? __expf(sv[i] - m) : 0.f;
        sum += pvv[i];
    }
#pragma unroll
    for (int off = 1; off < 64; off <<= 1) sum += __shfl_xor(sum, off, 64);
    float inv = (sum > 0.f) ? 1.f / sum : 0.f;  // masked q row: all-zero probs
#pragma unroll
    for (int i = 0; i < 4; ++i) pl[wid][lane + i * 64] = pvv[i] * inv;
    __syncthreads();

    float acc[QG] = {0.f, 0.f, 0.f, 0.f};
    const float* kp = keys + b * TK * DIM + t;  // coalesced: t = channel
#pragma unroll 4
    for (int k = 0; k < klen; ++k) {
        float kv = kp[k * DIM];
#pragma unroll
        for (int r = 0; r < QG; ++r) acc[r] = fmaf(pl[r][k], kv, acc[r]);
    }
#pragma unroll
    for (int r = 0; r < QG; ++r) out[(b * TQ + qg + r) * DIM + t] = acc[r];
}

extern "C" void kernel_launch(void* const* d_in, const int* in_sizes, int n_in,
                              void* d_out, int out_size, void* d_ws, size_t ws_size,
                              hipStream_t stream) {
    (void)in_sizes; (void)n_in; (void)out_size; (void)ws_size;
    const float* queries = (const float*)d_in[0];
    const float* keys    = (const float*)d_in[1];
    const int*   qlens   = (const int*)d_in[2];
    const int*   klens   = (const int*)d_in[3];
    const float* W1      = (const float*)d_in[4];
    const float* b1      = (const float*)d_in[5];
    const float* W2      = (const float*)d_in[6];
    const float* b2      = (const float*)d_in[7];
    const float* W3      = (const float*)d_in[8];
    const float* b3      = (const float*)d_in[9];
    float* out = (float*)d_out;

    float* qh     = (float*)d_ws;                 // 4*256*256 f32 = 1 MB (b1 folded)
    float* kh     = qh + BATCH * TQ * HD;         // 1 MB
    float* scores = kh + BATCH * TK * HD;         // 1 MB
    unsigned short* W2T = (unsigned short*)(scores + BATCH * TQ * TK);  // 128 KB

    prep_qk<<<256, 256, 0, stream>>>(queries, keys, W1, b1, qh, kh);
    w2_transpose<<<64, 256, 0, stream>>>(W2, W2T);
    mlp_scores<<<BATCH * TQ * (TK / 64), 256, 0, stream>>>(
        qh, kh, W2T, b2, W3, b3, qlens, klens, scores);
    softmax_pv<<<BATCH * (TQ / QG), 256, 0, stream>>>(scores, keys, qlens, klens, out);
}

// Round 3
// 150.012 us; speedup vs baseline: 1.1673x; 1.1169x over previous
//
#include <hip/hip_runtime.h>
#include <cstdint>

#define BATCH 4
#define TQ 256
#define TK 256
#define DIM 256
#define HD 256

typedef _Float16 f16x8 __attribute__((ext_vector_type(8)));
typedef float f32x4 __attribute__((ext_vector_type(4)));

union U4H8 { uint4 u; f16x8 v; };

__device__ __forceinline__ unsigned short f2h(float f) {
    _Float16 h = (_Float16)f;
    unsigned short u;
    __builtin_memcpy(&u, &h, 2);
    return u;
}

__device__ __forceinline__ uint32_t pk2h(float a, float b) {
    auto r = __builtin_amdgcn_cvt_pkrtz(a, b);
    uint32_t w;
    __builtin_memcpy(&w, &r, 4);
    return w;
}

// Fused prep: blocks 0..255  -> qh = queries@W1[256:]+b1, kh = keys@W1[:256]
//             blocks 256..319 -> W2T[n][c] = (f16)W2[c][n]
__global__ __launch_bounds__(256) void prep_all(
    const float* __restrict__ queries, const float* __restrict__ keys,
    const float* __restrict__ W1, const float* __restrict__ b1,
    const float* __restrict__ W2,
    float* __restrict__ qh, float* __restrict__ kh,
    unsigned short* __restrict__ W2T) {
    int i = blockIdx.x;
    int t = threadIdx.x;
    if (i >= 256) {  // ---- W2 transpose ----
        __shared__ float tile[32][33];
        int bi = i - 256;
        int tx = t & 31, ty = t >> 5;
        int tc = (bi & 7) * 32, tn = (bi >> 3) * 32;
#pragma unroll
        for (int r = 0; r < 4; ++r)
            tile[ty + r * 8][tx] = W2[(tc + ty + r * 8) * HD + tn + tx];
        __syncthreads();
#pragma unroll
        for (int r = 0; r < 4; ++r)
            W2T[(tn + ty + r * 8) * HD + tc + tx] = f2h(tile[tx][ty + r * 8]);
        return;
    }
    // ---- qh / kh ----
    bool isQ = i < 128;
    int r0 = (i & 127) * 8;
    const float* X = isQ ? queries : keys;
    const float* W = W1 + (isQ ? DIM * HD : 0);
    float* O = isQ ? qh : kh;
    __shared__ float xs[8][DIM];
#pragma unroll
    for (int r = 0; r < 8; ++r) xs[r][t] = X[(r0 + r) * DIM + t];
    __syncthreads();
    float acc[8] = {0.f, 0.f, 0.f, 0.f, 0.f, 0.f, 0.f, 0.f};
#pragma unroll 4
    for (int d = 0; d < DIM; ++d) {
        float w = W[d * HD + t];  // coalesced across t
#pragma unroll
        for (int r = 0; r < 8; ++r) acc[r] = fmaf(xs[r][d], w, acc[r]);
    }
    float bias = isQ ? b1[t] : 0.f;
#pragma unroll
    for (int r = 0; r < 8; ++r) O[(r0 + r) * HD + t] = acc[r] + bias;
}

// One block per (b,q): computes the whole 256-wide score row via MFMA
// (4 k-chunks of 64, double-buffered LDS A-staging, W2T slice resident in
// 128 VGPRs per wave), then masked softmax + PV in-block. b3 dropped
// (uniform score shift — softmax-invariant).
__global__ __launch_bounds__(256, 2) void mlp_attn(
    const float* __restrict__ qh, const float* __restrict__ kh,
    const unsigned short* __restrict__ W2T,
    const float* __restrict__ b2, const float* __restrict__ W3,
    const float* __restrict__ keys,
    const int* __restrict__ qlens, const int* __restrict__ klens,
    float* __restrict__ out) {
    int bid = blockIdx.x;
    int b = bid >> 8;
    int q = bid & 255;
    int t = threadIdx.x;
    float* orow = out + (b * TQ + q) * DIM;
    if (q >= qlens[b]) { orow[t] = 0.f; return; }   // uniform exit, zero row
    int klen = klens[b];
    int nch = (klen + 63) >> 6;   // 2..4 valid 64-wide k chunks

    __shared__ uint4 Afrag[2][8][4][64];  // [buf][k-step][m-tile][lane], 2x32KB
    __shared__ float srow[TK];            // score partials -> probs
    __shared__ float red[8];

    int wid = t >> 6, lane = t & 63;
    int col = lane & 15, quad = lane >> 4;

    // ---- load this wave's W2T slice into registers: 32 x uint4 = 128 VGPR ----
    int nb = wid * 64;
    uint4 bfr[4][8];
    float b2v[4], w3v[4];
#pragma unroll
    for (int nt = 0; nt < 4; ++nt) {
        int n = nb + nt * 16 + col;
        const uint4* r = (const uint4*)(W2T + n * HD) + quad;  // quad -> k-offset quad*8
#pragma unroll
        for (int s = 0; s < 8; ++s) bfr[nt][s] = r[s * 4];
        b2v[nt] = b2[n];
        w3v[nt] = W3[n];
    }

    // staging role: thread t -> chunk-row p = t>>2, c-octet j8 = t&3
    int p = t >> 2, j8 = t & 3;
    const float* qrow = qh + (b * TQ + q) * HD + j8 * 8;  // b1 pre-folded
    const float* kbase = kh + b * TK * HD + j8 * 8;
    int aoff = ((p >> 4) << 6) | (p & 15) | (j8 << 4);    // [mt][lane] flat index

    auto stage = [&](int c, int d) {   // stage chunk c into buffer d
        const float* krow = kbase + (c * 64 + p) * HD;
        uint4* aslot = &Afrag[d][0][0][0] + aoff;
#pragma unroll
        for (int s = 0; s < 8; ++s) {
            const float4 k0 = *(const float4*)(krow + s * 32);
            const float4 k1 = *(const float4*)(krow + s * 32 + 4);
            const float4 q0 = *(const float4*)(qrow + s * 32);
            const float4 q1 = *(const float4*)(qrow + s * 32 + 4);
            uint4 w;
            w.x = pk2h(fmaxf(k0.x + q0.x, 0.f), fmaxf(k0.y + q0.y, 0.f));
            w.y = pk2h(fmaxf(k0.z + q0.z, 0.f), fmaxf(k0.w + q0.w, 0.f));
            w.z = pk2h(fmaxf(k1.x + q1.x, 0.f), fmaxf(k1.y + q1.y, 0.f));
            w.w = pk2h(fmaxf(k1.z + q1.z, 0.f), fmaxf(k1.w + q1.w, 0.f));
            aslot[s * 256] = w;
        }
    };

    srow[t] = 0.f;        // score accumulator (atomic target)
    stage(0, 0);
    __syncthreads();      // buffer 0 staged, srow zeroed

    for (int c = 0; c < nch; ++c) {
        int cur = c & 1;
        if (c + 1 < nch) stage(c + 1, cur ^ 1);  // loads overlap MFMAs below

        f32x4 acc[4][4] = {};
#pragma unroll
        for (int s = 0; s < 8; ++s) {
#pragma unroll
            for (int mt = 0; mt < 4; ++mt) {
                U4H8 au;
                au.u = Afrag[cur][s][mt][lane];
#pragma unroll
                for (int nt = 0; nt < 4; ++nt) {
                    U4H8 bu;
                    bu.u = bfr[nt][s];
                    acc[mt][nt] = __builtin_amdgcn_mfma_f32_16x16x32_f16(
                        au.v, bu.v, acc[mt][nt], 0, 0, 0);
                }
            }
        }

        // epilogue: relu(+b2) * W3, reduce over n (16 cols then cross-wave atomic)
#pragma unroll
        for (int mt = 0; mt < 4; ++mt) {
            float part[4];
#pragma unroll
            for (int r = 0; r < 4; ++r) {
                float pa = 0.f;
#pragma unroll
                for (int nt = 0; nt < 4; ++nt)
                    pa = fmaf(fmaxf(acc[mt][nt][r] + b2v[nt], 0.f), w3v[nt], pa);
                part[r] = pa;
            }
#pragma unroll
            for (int off = 1; off < 16; off <<= 1)
#pragma unroll
                for (int r = 0; r < 4; ++r)
                    part[r] += __shfl_xor(part[r], off, 64);
            if (col == 0)
#pragma unroll
                for (int r = 0; r < 4; ++r)
                    atomicAdd(&srow[c * 64 + mt * 16 + quad * 4 + r], part[r]);
        }
        __syncthreads();  // stage(c+1) visible, atomics done, buf cur free
    }

    // ---- masked softmax over srow ----
    float s = (t < klen) ? srow[t] : -3.4e38f;
    float m = s;
#pragma unroll
    for (int off = 1; off < 64; off <<= 1) m = fmaxf(m, __shfl_xor(m, off, 64));
    if (lane == 0) red[wid] = m;
    __syncthreads();
    m = fmaxf(fmaxf(red[0], red[1]), fmaxf(red[2], red[3]));
    float e = (t < klen) ? __expf(s - m) : 0.f;
    float sum = e;
#pragma unroll
    for (int off = 1; off < 64; off <<= 1) sum += __shfl_xor(sum, off, 64);
    if (lane == 0) red[4 + wid] = sum;
    __syncthreads();
    float denom = red[4] + red[5] + red[6] + red[7];
    srow[t] = e / denom;   // probs
    __syncthreads();

    // ---- PV: out[d=t] = sum_k probs[k] * keys[b][k][t] ----
    float acc = 0.f;
    const float* kp = keys + b * TK * DIM + t;  // coalesced: t = channel
#pragma unroll 8
    for (int k = 0; k < klen; ++k) acc = fmaf(srow[k], kp[k * DIM], acc);
    orow[t] = acc;
}

extern "C" void kernel_launch(void* const* d_in, const int* in_sizes, int n_in,
                              void* d_out, int out_size, void* d_ws, size_t ws_size,
                              hipStream_t stream) {
    (void)in_sizes; (void)n_in; (void)out_size; (void)ws_size;
    const float* queries = (const float*)d_in[0];
    const float* keys    = (const float*)d_in[1];
    const int*   qlens   = (const int*)d_in[2];
    const int*   klens   = (const int*)d_in[3];
    const float* W1      = (const float*)d_in[4];
    const float* b1      = (const float*)d_in[5];
    const float* W2      = (const float*)d_in[6];
    const float* b2      = (const float*)d_in[7];
    const float* W3      = (const float*)d_in[8];
    float* out = (float*)d_out;

    float* qh = (float*)d_ws;                     // 4*256*256 f32 = 1 MB (b1 folded)
    float* kh = qh + BATCH * TQ * HD;             // 1 MB
    unsigned short* W2T = (unsigned short*)(kh + BATCH * TK * HD);  // 128 KB

    prep_all<<<320, 256, 0, stream>>>(queries, keys, W1, b1, W2, qh, kh, W2T);
    mlp_attn<<<BATCH * TQ, 256, 0, stream>>>(
        qh, kh, W2T, b2, W3, keys, qlens, klens, out);
}

// Round 4
// 143.669 us; speedup vs baseline: 1.2188x; 1.0441x over previous
//
#include <hip/hip_runtime.h>
#include <cstdint>

#define BATCH 4
#define TQ 256
#define TK 256
#define DIM 256
#define HD 256

typedef _Float16 f16x8 __attribute__((ext_vector_type(8)));
typedef float f32x4 __attribute__((ext_vector_type(4)));

union U4H8 { uint4 u; f16x8 v; };

// Opaque def+use: forces the value to be materialized in a VGPR here and
// prevents the compiler from sinking/rematerializing the producing load.
#define KEEP(x) asm volatile("" : "+v"(x))

__device__ __forceinline__ unsigned short f2h(float f) {
    _Float16 h = (_Float16)f;
    unsigned short u;
    __builtin_memcpy(&u, &h, 2);
    return u;
}

__device__ __forceinline__ uint32_t pk2h(float a, float b) {
    auto r = __builtin_amdgcn_cvt_pkrtz(a, b);
    uint32_t w;
    __builtin_memcpy(&w, &r, 4);
    return w;
}

// Fused prep: blocks 0..255  -> qh = queries@W1[256:]+b1, kh = keys@W1[:256]
//             blocks 256..319 -> W2T[n][c] = (f16)W2[c][n]
__global__ __launch_bounds__(256) void prep_all(
    const float* __restrict__ queries, const float* __restrict__ keys,
    const float* __restrict__ W1, const float* __restrict__ b1,
    const float* __restrict__ W2,
    float* __restrict__ qh, float* __restrict__ kh,
    unsigned short* __restrict__ W2T) {
    int i = blockIdx.x;
    int t = threadIdx.x;
    if (i >= 256) {  // ---- W2 transpose ----
        __shared__ float tile[32][33];
        int bi = i - 256;
        int tx = t & 31, ty = t >> 5;
        int tc = (bi & 7) * 32, tn = (bi >> 3) * 32;
#pragma unroll
        for (int r = 0; r < 4; ++r)
            tile[ty + r * 8][tx] = W2[(tc + ty + r * 8) * HD + tn + tx];
        __syncthreads();
#pragma unroll
        for (int r = 0; r < 4; ++r)
            W2T[(tn + ty + r * 8) * HD + tc + tx] = f2h(tile[tx][ty + r * 8]);
        return;
    }
    // ---- qh / kh ----
    bool isQ = i < 128;
    int r0 = (i & 127) * 8;
    const float* X = isQ ? queries : keys;
    const float* W = W1 + (isQ ? DIM * HD : 0);
    float* O = isQ ? qh : kh;
    __shared__ float xs[8][DIM];
#pragma unroll
    for (int r = 0; r < 8; ++r) xs[r][t] = X[(r0 + r) * DIM + t];
    __syncthreads();
    float acc[8] = {0.f, 0.f, 0.f, 0.f, 0.f, 0.f, 0.f, 0.f};
#pragma unroll 8
    for (int d = 0; d < DIM; ++d) {
        float w = W[d * HD + t];  // coalesced across t; 8 loads in flight
#pragma unroll
        for (int r = 0; r < 8; ++r) acc[r] = fmaf(xs[r][d], w, acc[r]);
    }
    float bias = isQ ? b1[t] : 0.f;
#pragma unroll
    for (int r = 0; r < 8; ++r) O[(r0 + r) * HD + t] = acc[r] + bias;
}

// One block per (b,q): MFMA score row (4 k-chunks, double-buffered LDS A,
// W2T slice pinned in 128 VGPRs/wave), then masked softmax + PV in-block.
__global__ __launch_bounds__(256, 2) void mlp_attn(
    const float* __restrict__ qh, const float* __restrict__ kh,
    const unsigned short* __restrict__ W2T,
    const float* __restrict__ b2, const float* __restrict__ W3,
    const float* __restrict__ keys,
    const int* __restrict__ qlens, const int* __restrict__ klens,
    float* __restrict__ out) {
    int bid = blockIdx.x;
    int b = bid >> 8;
    int q = bid & 255;
    int t = threadIdx.x;
    float* orow = out + (b * TQ + q) * DIM;
    if (q >= qlens[b]) { orow[t] = 0.f; return; }   // uniform exit, zero row
    int klen = klens[b];
    int nch = (klen + 63) >> 6;   // 2..4 valid 64-wide k chunks

    __shared__ uint4 Afrag[2][8][4][64];  // [buf][k-step][m-tile][lane], 2x32KB
    __shared__ float srow[TK];            // score partials -> probs
    __shared__ float red[8];

    int wid = t >> 6, lane = t & 63;
    int col = lane & 15, quad = lane >> 4;

    // ---- issue this wave's W2T slice loads: 32 x uint4 = 128 VGPR ----
    int nb = wid * 64;
    uint4 bfr[4][8];
    float b2v[4], w3v[4];
#pragma unroll
    for (int nt = 0; nt < 4; ++nt) {
        int n = nb + nt * 16 + col;
        const uint4* r = (const uint4*)(W2T + n * HD) + quad;  // quad -> k-offset quad*8
#pragma unroll
        for (int s = 0; s < 8; ++s) bfr[nt][s] = r[s * 4];
        b2v[nt] = b2[n];
        w3v[nt] = W3[n];
    }

    // staging role: thread t -> chunk-row p = t>>2, c-octet j8 = t&3
    int p = t >> 2, j8 = t & 3;
    const float* qrow = qh + (b * TQ + q) * HD + j8 * 8;  // b1 pre-folded
    const float* kbase = kh + b * TK * HD + j8 * 8;
    int aoff = ((p >> 4) << 6) | (p & 15) | (j8 << 4);    // [mt][lane] flat index

    auto stage = [&](int c, int d) {   // stage chunk c into buffer d
        const float* krow = kbase + (c * 64 + p) * HD;
        uint4* aslot = &Afrag[d][0][0][0] + aoff;
#pragma unroll 2
        for (int s = 0; s < 8; ++s) {
            const float4 k0 = *(const float4*)(krow + s * 32);
            const float4 k1 = *(const float4*)(krow + s * 32 + 4);
            const float4 q0 = *(const float4*)(qrow + s * 32);
            const float4 q1 = *(const float4*)(qrow + s * 32 + 4);
            uint4 w;
            w.x = pk2h(fmaxf(k0.x + q0.x, 0.f), fmaxf(k0.y + q0.y, 0.f));
            w.y = pk2h(fmaxf(k0.z + q0.z, 0.f), fmaxf(k0.w + q0.w, 0.f));
            w.z = pk2h(fmaxf(k1.x + q1.x, 0.f), fmaxf(k1.y + q1.y, 0.f));
            w.w = pk2h(fmaxf(k1.z + q1.z, 0.f), fmaxf(k1.w + q1.w, 0.f));
            aslot[s * 256] = w;
        }
    };

    srow[t] = 0.f;        // score accumulator (atomic target)
    stage(0, 0);

    // Pin the B slice: after this point bfr is opaque-defined -> cannot be
    // sunk into the loop or rematerialized as in-loop global loads.
#pragma unroll
    for (int nt = 0; nt < 4; ++nt)
#pragma unroll
        for (int s = 0; s < 8; ++s) {
            KEEP(bfr[nt][s].x); KEEP(bfr[nt][s].y);
            KEEP(bfr[nt][s].z); KEEP(bfr[nt][s].w);
        }

    __syncthreads();      // buffer 0 staged, srow zeroed

    for (int c = 0; c < nch; ++c) {
        int cur = c & 1;
        if (c + 1 < nch) stage(c + 1, cur ^ 1);  // loads overlap MFMAs below

        f32x4 acc[4][4] = {};
#pragma unroll
        for (int s = 0; s < 8; ++s) {
#pragma unroll
            for (int mt = 0; mt < 4; ++mt) {
                U4H8 au;
                au.u = Afrag[cur][s][mt][lane];
#pragma unroll
                for (int nt = 0; nt < 4; ++nt) {
                    U4H8 bu;
                    bu.u = bfr[nt][s];
                    acc[mt][nt] = __builtin_amdgcn_mfma_f32_16x16x32_f16(
                        au.v, bu.v, acc[mt][nt], 0, 0, 0);
                }
            }
        }

        // epilogue: relu(+b2) * W3, reduce over n (16 cols then cross-wave atomic)
#pragma unroll
        for (int mt = 0; mt < 4; ++mt) {
            float part[4];
#pragma unroll
            for (int r = 0; r < 4; ++r) {
                float pa = 0.f;
#pragma unroll
                for (int nt = 0; nt < 4; ++nt)
                    pa = fmaf(fmaxf(acc[mt][nt][r] + b2v[nt], 0.f), w3v[nt], pa);
                part[r] = pa;
            }
#pragma unroll
            for (int off = 1; off < 16; off <<= 1)
#pragma unroll
                for (int r = 0; r < 4; ++r)
                    part[r] += __shfl_xor(part[r], off, 64);
            if (col == 0)
#pragma unroll
                for (int r = 0; r < 4; ++r)
                    atomicAdd(&srow[c * 64 + mt * 16 + quad * 4 + r], part[r]);
        }
        __syncthreads();  // stage(c+1) visible, atomics done, buf cur free
    }

    // ---- masked softmax over srow ----
    float s = (t < klen) ? srow[t] : -3.4e38f;
    float m = s;
#pragma unroll
    for (int off = 1; off < 64; off <<= 1) m = fmaxf(m, __shfl_xor(m, off, 64));
    if (lane == 0) red[wid] = m;
    __syncthreads();
    m = fmaxf(fmaxf(red[0], red[1]), fmaxf(red[2], red[3]));
    float e = (t < klen) ? __expf(s - m) : 0.f;
    float sum = e;
#pragma unroll
    for (int off = 1; off < 64; off <<= 1) sum += __shfl_xor(sum, off, 64);
    if (lane == 0) red[4 + wid] = sum;
    __syncthreads();
    float denom = red[4] + red[5] + red[6] + red[7];
    srow[t] = e / denom;   // probs
    __syncthreads();

    // ---- PV: out[d=t] = sum_k probs[k] * keys[b][k][t] ----
    float acc = 0.f;
    const float* kp = keys + b * TK * DIM + t;  // coalesced: t = channel
#pragma unroll 8
    for (int k = 0; k < klen; ++k) acc = fmaf(srow[k], kp[k * DIM], acc);
    orow[t] = acc;
}

extern "C" void kernel_launch(void* const* d_in, const int* in_sizes, int n_in,
                              void* d_out, int out_size, void* d_ws, size_t ws_size,
                              hipStream_t stream) {
    (void)in_sizes; (void)n_in; (void)out_size; (void)ws_size;
    const float* queries = (const float*)d_in[0];
    const float* keys    = (const float*)d_in[1];
    const int*   qlens   = (const int*)d_in[2];
    const int*   klens   = (const int*)d_in[3];
    const float* W1      = (const float*)d_in[4];
    const float* b1      = (const float*)d_in[5];
    const float* W2      = (const float*)d_in[6];
    const float* b2      = (const float*)d_in[7];
    const float* W3      = (const float*)d_in[8];
    float* out = (float*)d_out;

    float* qh = (float*)d_ws;                     // 4*256*256 f32 = 1 MB (b1 folded)
    float* kh = qh + BATCH * TQ * HD;             // 1 MB
    unsigned short* W2T = (unsigned short*)(kh + BATCH * TK * HD);  // 128 KB

    prep_all<<<320, 256, 0, stream>>>(queries, keys, W1, b1, W2, qh, kh, W2T);
    mlp_attn<<<BATCH * TQ, 256, 0, stream>>>(
        qh, kh, W2T, b2, W3, keys, qlens, klens, out);
}